// Round 10
// baseline (10567.008 us; speedup 1.0000x reference)
//
#include <hip/hip_runtime.h>
#include <math.h>

#define BB 128
#define TT 512
#define FF 128
#define HH 512
#define NR 2048      // gate rows, row = 4*j + g
#define TC 16        // timesteps per rec launch
#define HB (HH*BB)   // 65536 elements per h state / c state

typedef __attribute__((ext_vector_type(8))) short short8;   // 8 bf16 (A/B frag)
typedef __attribute__((ext_vector_type(4))) float f32x4;    // MFMA C/D frag
typedef unsigned int uint;
typedef unsigned short ushort;
typedef unsigned long long ull;

__device__ __forceinline__ ushort f2bf(float f) {           // fp32 -> bf16 RNE
  uint u = __float_as_uint(f);
  u += 0x7fff + ((u >> 16) & 1);
  return (ushort)(u >> 16);
}

// ---------------- prep kernels ----------------

__global__ __launch_bounds__(256) void k_zero(float* __restrict__ p, int n) {
  int i = blockIdx.x * 256 + threadIdx.x;
  if (i < n) p[i] = 0.f;
}

// W[k][col] (col = g*512 + j) -> Wp[k][4j+g]; also used for bias (n=2048)
__global__ __launch_bounds__(256) void k_rearr_W(const float* __restrict__ src,
                                                 float* __restrict__ dst, int n) {
  int idx = blockIdx.x * 256 + threadIdx.x;
  if (idx >= n) return;
  int k = idx >> 11, col = idx & 2047;
  int j = col & 511, g = col >> 9;
  dst[k * NR + j * 4 + g] = src[idx];
}

// [512][2048] matrix (U or W2) -> A-fragment order, bf16 hi/lo split.
__global__ __launch_bounds__(256) void k_pack_U(const float* __restrict__ src,
                                                ushort* __restrict__ dst) {
  int idx = blockIdx.x * 256 + threadIdx.x;   // over 128*16*64*8 = 1048576
  int j8 = idx & 7;
  int L = (idx >> 3) & 63;
  int kt = (idx >> 9) & 15;
  int jb = idx >> 13;
  int k = kt * 32 + (L >> 4) * 8 + j8;
  int m = L & 15;
  int j = jb * 4 + (m >> 2);
  int g = m & 3;
  float v = src[k * NR + g * HH + j];
  ushort hi = f2bf(v);
  float fhi = __uint_as_float(((uint)hi) << 16);
  ushort lo = f2bf(v - fhi);
  size_t base = ((size_t)(jb * 16 + kt) * 64 + L) * 16;
  dst[base + j8] = hi;
  dst[base + 8 + j8] = lo;
}

// ---------------- layer-1 projection GEMM (VALU, fp32 x input) ----------------
__global__ __launch_bounds__(256) void k_proj1(const float* __restrict__ in,
                                               const float* __restrict__ Wp,
                                               const float* __restrict__ bp,
                                               float4* __restrict__ xz4, int t0) {
  __shared__ float Wt[16 * 68];
  __shared__ float Xs[16 * 132];
  int tid = threadIdx.x;
  int r0 = blockIdx.x * 64;
  int tl = blockIdx.y;
  int ty = tid >> 5, tx = tid & 31;
  float acc[8][4];
#pragma unroll
  for (int i = 0; i < 8; ++i)
#pragma unroll
    for (int j = 0; j < 4; ++j) acc[i][j] = 0.f;

  int wi = (tid * 4) >> 6, wr = (tid * 4) & 63;
  int bb0 = tid >> 1, half0 = tid & 1;

  float4 wreg;
  float xf[8];
  {
    wreg = *(const float4*)(Wp + (size_t)wi * NR + r0 + wr);
    const float* src = in + (size_t)bb0 * (TT * FF) + (size_t)(t0 + tl) * FF + half0 * 8;
    float4 v0 = *(const float4*)(src);
    float4 v1 = *(const float4*)(src + 4);
    xf[0]=v0.x; xf[1]=v0.y; xf[2]=v0.z; xf[3]=v0.w;
    xf[4]=v1.x; xf[5]=v1.y; xf[6]=v1.z; xf[7]=v1.w;
  }

  for (int k0 = 0; k0 < FF; k0 += 16) {
    __syncthreads();
    *(float4*)&Wt[wi * 68 + wr] = wreg;
#pragma unroll
    for (int q = 0; q < 8; ++q) Xs[(half0 * 8 + q) * 132 + bb0] = xf[q];
    __syncthreads();
    if (k0 + 16 < FF) {
      wreg = *(const float4*)(Wp + (size_t)(k0 + 16 + wi) * NR + r0 + wr);
      const float* src = in + (size_t)bb0 * (TT * FF) + (size_t)(t0 + tl) * FF + k0 + 16 + half0 * 8;
      float4 v0 = *(const float4*)(src);
      float4 v1 = *(const float4*)(src + 4);
      xf[0]=v0.x; xf[1]=v0.y; xf[2]=v0.z; xf[3]=v0.w;
      xf[4]=v1.x; xf[5]=v1.y; xf[6]=v1.z; xf[7]=v1.w;
    }
#pragma unroll
    for (int k = 0; k < 16; ++k) {
      float4 wA = *(const float4*)&Wt[k * 68 + ty * 8];
      float4 wB = *(const float4*)&Wt[k * 68 + ty * 8 + 4];
      float4 xA = *(const float4*)&Xs[k * 132 + tx * 4];
      float w[8] = {wA.x, wA.y, wA.z, wA.w, wB.x, wB.y, wB.z, wB.w};
      float xv[4] = {xA.x, xA.y, xA.z, xA.w};
#pragma unroll
      for (int i = 0; i < 8; ++i)
#pragma unroll
        for (int j = 0; j < 4; ++j) acc[i][j] = fmaf(w[i], xv[j], acc[i][j]);
    }
  }
#pragma unroll
  for (int jj = 0; jj < 2; ++jj) {
    int j = (r0 >> 2) + ty * 2 + jj;
    float bv0 = bp[r0 + ty * 8 + jj * 4 + 0];
    float bv1 = bp[r0 + ty * 8 + jj * 4 + 1];
    float bv2 = bp[r0 + ty * 8 + jj * 4 + 2];
    float bv3 = bp[r0 + ty * 8 + jj * 4 + 3];
#pragma unroll
    for (int c = 0; c < 4; ++c) {
      float4 o = {acc[jj * 4 + 0][c] + bv0, acc[jj * 4 + 1][c] + bv1,
                  acc[jj * 4 + 2][c] + bv2, acc[jj * 4 + 3][c] + bv3};
      xz4[((size_t)tl * HH + j) * BB + tx * 4 + c] = o;
    }
  }
}

// ---------------- layer-2 projection GEMM (MFMA, packed-bf16 h input) ----------------
__global__ __launch_bounds__(256) void k_proj2(const uint* __restrict__ hw,
                                               const ushort* __restrict__ Wpk,
                                               const float* __restrict__ bp,
                                               float4* __restrict__ xz4) {
  int tid = threadIdx.x;
  int L = tid & 63;
  int w = tid >> 6;
  int jbp = blockIdx.x * 4 + w;
  int tl = blockIdx.y;
  int q = L >> 4, n = L & 15;
  const uint* hb = hw + (size_t)tl * HB;
  f32x4 acc[8];
#pragma unroll
  for (int ct = 0; ct < 8; ++ct) acc[ct] = (f32x4){0.f, 0.f, 0.f, 0.f};

  for (int kt = 0; kt < 16; ++kt) {
    const ushort* ub = Wpk + ((size_t)(jbp * 16 + kt) * 64 + L) * 16;
    short8 uh = *(const short8*)(ub);
    short8 ul = *(const short8*)(ub + 8);
#pragma unroll
    for (int ct = 0; ct < 8; ++ct) {
      uint wv[8];
#pragma unroll
      for (int u = 0; u < 8; ++u)
        wv[u] = hb[(size_t)(kt * 32 + q * 8 + u) * BB + ct * 16 + n];
      short8 bhi, blo;
#pragma unroll
      for (int u = 0; u < 8; ++u) {
        bhi[u] = (short)(wv[u] >> 16);
        blo[u] = (short)(wv[u] & 0xffffu);
      }
      acc[ct] = __builtin_amdgcn_mfma_f32_16x16x32_bf16(uh, bhi, acc[ct], 0, 0, 0);
      acc[ct] = __builtin_amdgcn_mfma_f32_16x16x32_bf16(ul, bhi, acc[ct], 0, 0, 0);
      acc[ct] = __builtin_amdgcn_mfma_f32_16x16x32_bf16(uh, blo, acc[ct], 0, 0, 0);
    }
  }
  int j = jbp * 4 + q;
  float4 bv = *(const float4*)(bp + j * 4);
#pragma unroll
  for (int ct = 0; ct < 8; ++ct) {
    float4 o = {acc[ct].x + bv.x, acc[ct].y + bv.y, acc[ct].z + bv.z, acc[ct].w + bv.w};
    xz4[((size_t)tl * HH + j) * BB + ct * 16 + n] = o;
  }
}

// ---------------- persistent recurrent kernel (MFMA, tagged-ring dataflow) ----------
// Grid 256 x 256 (1 block/CU). Block bx = jb*2+bh; 4 waves = 4 col-tiles of 16.
// NO barriers, NO flags: h states live in a 16-slot ring of {word,tag} u64
// written via single 8B agent atomic stores (tag = t+1, monotone). Consumers
// issue tagged loads and verify tag >= t per element, retrying on miss —
// the data is its own flag; stale reads self-correct via retry, so no
// fences are needed. `>=` keeps rocprof replay terminating (tags already
// final -> instant pass). Ring-reuse safe: a block reaches step t+15 only
// after all same-half blocks completed t+14, so no tag-t reader can coexist
// with the overwrite of its slot. 4-deep batch prefetch hides L3 latency.
__global__ __launch_bounds__(256, 1) void k_rec(const ushort* __restrict__ Upk,
                                                const float4* __restrict__ xz4,
                                                ull* __restrict__ ring,
                                                uint* __restrict__ seqout,
                                                float* __restrict__ cT,
                                                int base) {
  int tid = threadIdx.x;
  int L = tid & 63;
  int ct = tid >> 6;            // wave id = col tile
  int jb = blockIdx.x >> 1;
  int bh = blockIdx.x & 1;
  int q = L >> 4, n = L & 15;
  int col = bh * 64 + ct * 16 + n;
  int j = jb * 4 + q;           // this lane's hidden unit (tail)
  int hrow = q * 8;             // B-frag k-offset within a 32-k tile

  // U fragments: 16 kt x (hi,lo) = 128 VGPRs, loaded once
  short8 uh[16], ul[16];
  {
    const ushort* ub = Upk + ((size_t)(jb * 16) * 64 + L) * 16;
#pragma unroll
    for (int kt = 0; kt < 16; ++kt) {
      uh[kt] = *(const short8*)(ub + (size_t)kt * 1024);
      ul[kt] = *(const short8*)(ub + (size_t)kt * 1024 + 8);
    }
  }
  float c_reg = cT[j * BB + col];

  for (int s = 0; s < TC; ++s) {
    int t = base + s;
    float4 xzv = xz4[((size_t)s * HH + j) * BB + col];   // stable memory
    const ull* __restrict__ rs = ring + (size_t)((t - 1) & 15) * HB + col;
    ull buf[4][8];
#pragma unroll
    for (int p = 0; p < 3; ++p)
#pragma unroll
      for (int u = 0; u < 8; ++u)
        buf[p][u] = __hip_atomic_load(&rs[(size_t)(p * 32 + hrow + u) * BB],
                                      __ATOMIC_RELAXED, __HIP_MEMORY_SCOPE_AGENT);
    f32x4 a0 = {0.f, 0.f, 0.f, 0.f};
    f32x4 a1 = {0.f, 0.f, 0.f, 0.f};
    f32x4 a2 = {0.f, 0.f, 0.f, 0.f};
#pragma unroll
    for (int kt = 0; kt < 16; ++kt) {
      if (kt < 13) {
#pragma unroll
        for (int u = 0; u < 8; ++u)
          buf[(kt + 3) & 3][u] =
              __hip_atomic_load(&rs[(size_t)((kt + 3) * 32 + hrow + u) * BB],
                                __ATOMIC_RELAXED, __HIP_MEMORY_SCOPE_AGENT);
      }
      // verify batch kt (retry on stale tags)
      while (1) {
        int ok = 1;
#pragma unroll
        for (int u = 0; u < 8; ++u) ok &= ((int)(buf[kt & 3][u] >> 32) >= t);
        if (__all(ok)) break;
#pragma unroll
        for (int u = 0; u < 8; ++u)
          buf[kt & 3][u] = __hip_atomic_load(&rs[(size_t)(kt * 32 + hrow + u) * BB],
                                             __ATOMIC_RELAXED, __HIP_MEMORY_SCOPE_AGENT);
      }
      short8 bhi, blo;
#pragma unroll
      for (int u = 0; u < 8; ++u) {
        uint w = (uint)buf[kt & 3][u];
        bhi[u] = (short)(w >> 16);
        blo[u] = (short)(w & 0xffffu);
      }
      a0 = __builtin_amdgcn_mfma_f32_16x16x32_bf16(uh[kt], bhi, a0, 0, 0, 0);
      a1 = __builtin_amdgcn_mfma_f32_16x16x32_bf16(ul[kt], bhi, a1, 0, 0, 0);
      a2 = __builtin_amdgcn_mfma_f32_16x16x32_bf16(uh[kt], blo, a2, 0, 0, 0);
    }
    float z0 = a0.x + a1.x + a2.x + xzv.x;
    float z1 = a0.y + a1.y + a2.y + xzv.y;
    float z2 = a0.z + a1.z + a2.z + xzv.z;
    float z3 = a0.w + a1.w + a2.w + xzv.w;
    float ig = 1.f / (1.f + __expf(-z0));
    float fg = 1.f / (1.f + __expf(-z1));
    float gg = tanhf(z2);
    float og = 1.f / (1.f + __expf(-z3));
    c_reg = fg * c_reg + ig * gg;
    float hn = og * tanhf(c_reg);
    ushort hi = f2bf(hn);
    float fhi = __uint_as_float(((uint)hi) << 16);
    ushort lo = f2bf(hn - fhi);
    uint word = (((uint)hi) << 16) | (uint)lo;
    ull v = (ull)word | (((ull)(uint)(t + 1)) << 32);
    __hip_atomic_store(&ring[(size_t)(t & 15) * HB + (size_t)j * BB + col], v,
                       __ATOMIC_RELAXED, __HIP_MEMORY_SCOPE_AGENT);
    if (seqout) seqout[(size_t)s * HB + (size_t)j * BB + col] = word;
  }
  cT[j * BB + col] = c_reg;
}

// ---------------- dense + softmax ----------------
__global__ __launch_bounds__(64) void k_dense(const ull* __restrict__ hslot,
                                              const float* __restrict__ Wd,
                                              const float* __restrict__ bd,
                                              float* __restrict__ out) {
  int b = blockIdx.x * 64 + threadIdx.x;
  float acc[10];
#pragma unroll
  for (int c = 0; c < 10; ++c) acc[c] = bd[c];
  for (int k = 0; k < HH; ++k) {
    uint w = (uint)__hip_atomic_load(&hslot[(size_t)k * BB + b],
                                     __ATOMIC_RELAXED, __HIP_MEMORY_SCOPE_AGENT);
    float hv = __uint_as_float(w & 0xffff0000u) + __uint_as_float(w << 16);
#pragma unroll
    for (int c = 0; c < 10; ++c) acc[c] = fmaf(hv, Wd[k * 10 + c], acc[c]);
  }
  float m = acc[0];
#pragma unroll
  for (int c = 1; c < 10; ++c) m = fmaxf(m, acc[c]);
  float s = 0.f;
#pragma unroll
  for (int c = 0; c < 10; ++c) { acc[c] = __expf(acc[c] - m); s += acc[c]; }
  float inv = 1.f / s;
#pragma unroll
  for (int c = 0; c < 10; ++c) out[b * 10 + c] = acc[c] * inv;
}

// ---------------- host ----------------
extern "C" void kernel_launch(void* const* d_in, const int* in_sizes, int n_in,
                              void* d_out, int out_size, void* d_ws, size_t ws_size,
                              hipStream_t stream) {
  const float* x  = (const float*)d_in[0];
  const float* W1 = (const float*)d_in[1];
  const float* U1 = (const float*)d_in[2];
  const float* b1 = (const float*)d_in[3];
  const float* W2 = (const float*)d_in[4];
  const float* U2 = (const float*)d_in[5];
  const float* b2 = (const float*)d_in[6];
  const float* Wd = (const float*)d_in[7];
  const float* bd = (const float*)d_in[8];
  float* out = (float*)d_out;

  // layout (4-byte units; every section size even -> ring stays 8B-aligned)
  uint*   seq  = (uint*)d_ws;                       // [512][HB] packed h   33,554,432
  float4* xz4  = (float4*)(seq + (size_t)TT * HB);  // [16][512][128] f4     4,194,304
  float*  Wp1  = (float*)(xz4 + (size_t)TC * HH * BB);   //     262,144
  float*  bp1  = Wp1 + (size_t)FF * NR;             //       2,048
  float*  bp2  = bp1 + NR;                          //       2,048
  ushort* Up1  = (ushort*)(bp2 + NR);               //   2,097,152 shorts
  ushort* Up2  = Up1 + (size_t)2097152;             //   2,097,152 shorts
  ushort* W2pk = Up2 + (size_t)2097152;             //   2,097,152 shorts
  ull*    ring = (ull*)(W2pk + (size_t)2097152);    // [16][HB] u64          2,097,152 u64
  float*  cT   = (float*)(ring + (size_t)TC * HB);  //      65,536
  // total ~43.4M 4B-units ~173 MB (<= R3's proven 181 MB)

  // prep (every call; ring zeroing gives tag 0 == "state before step 0", h0 = 0)
  k_zero<<<(HB + 255) / 256, 256, 0, stream>>>(cT, HB);
  k_zero<<<(TC * HB * 2 + 255) / 256, 256, 0, stream>>>((float*)ring, TC * HB * 2);
  k_rearr_W<<<(FF * NR) / 256, 256, 0, stream>>>(W1, Wp1, FF * NR);
  k_rearr_W<<<NR / 256, 256, 0, stream>>>(b1, bp1, NR);
  k_rearr_W<<<NR / 256, 256, 0, stream>>>(b2, bp2, NR);
  k_pack_U<<<4096, 256, 0, stream>>>(U1, Up1);
  k_pack_U<<<4096, 256, 0, stream>>>(U2, Up2);
  k_pack_U<<<4096, 256, 0, stream>>>(W2, W2pk);

  // layer 1: global steps t = 0..511; h words also written to seq[t] for proj2
  for (int c = 0; c < TT / TC; ++c) {
    int t0 = c * TC;
    k_proj1<<<dim3(NR / 64, TC), 256, 0, stream>>>(x, Wp1, bp1, xz4, t0);
    k_rec<<<256, 256, 0, stream>>>(Up1, xz4, ring, seq + (size_t)t0 * HB, cT, t0);
  }
  // layer 2: global steps t = 512..1023 (initial h,c = layer-1 final, via ring/cT)
  for (int c = 0; c < TT / TC; ++c) {
    int t0 = c * TC;
    k_proj2<<<dim3(32, TC), 256, 0, stream>>>(seq + (size_t)t0 * HB, W2pk, bp2, xz4);
    k_rec<<<256, 256, 0, stream>>>(Up2, xz4, ring, (uint*)nullptr, cT, TT + t0);
  }
  // final h2 = state after t=1023 -> ring slot 1023 & 15 = 15
  k_dense<<<BB / 64, 64, 0, stream>>>(ring + (size_t)15 * HB, Wd, bd, out);
}